// Round 17
// baseline (152.065 us; speedup 1.0000x reference)
//
#include <hip/hip_runtime.h>

// EnhancedMemoryStack: B=32768, S=16, D=64. fp32 I/O; bf16 MFMA internally.
//
// Algebra:
//   scores = xhat (Q K^T) xhat^T = xhat M xhat^T, with M = Q K^T (128x128) precomputed.
//   z_read = sum_t w[t] vhat[t],  w[t] = sum_s (np[s]/rowsum[s]) e[s][t]  (softmax folded)
//
// R17 = R16 (146.3us session-best) + DUAL-BATCH per wave (clean retest of R3's ILP
// idea without its register blowup):
//   - sequential coalesced staging: stage A -> read afA; stage B reuses the same 4KB
//     buffer (same-wave DS is in-order) -> afB. No doubled load buffers (R16 staging
//     has no cz[8]; cm[8] transient).
//   - shared weight fragments: each Mt/Wv ds_read feeds BOTH batches' MFMAs
//     (halves DS reads per batch, 2x independent MFMA chains per lgkm wait).
//   - half-SY dual (R7-proven 2KB layout): y in 2 halves; SYA=[0..2KB) SYB=[2KB..4KB)
//     -> still 4KB/wave, LDS map and 2 WG/CU unchanged.
//   - 4 outer iterations of batch pairs; stagger step doubled (s_sleep(88)).
//
// 512-thr WG (8 waves): LDS = M(32K)+Wv(16K)+8x4K = 80KB -> 2 WG/CU.
// d_ws: [0..4) counter, [1024..33792) Mt row-major bf16 (ws_size >= 33792).

typedef __bf16 bf16x8 __attribute__((ext_vector_type(8)));
typedef float  f32x4  __attribute__((ext_vector_type(4)));
typedef float  f4     __attribute__((ext_vector_type(4)));

#define B_TOT   32768
#define GRID_WG 512
#define NWAVES  4096
#define PAIRS   4
#define LOG2E   1.4426950408889634f
#define EXSC    0.18033688011112042f   // 0.125 * log2(e)

__device__ __forceinline__ unsigned short f2bf(float x) {
  __bf16 h = (__bf16)x;
  return __builtin_bit_cast(unsigned short, h);
}
__device__ __forceinline__ float rcp_f(float x) { return __builtin_amdgcn_rcpf(x); }
__device__ __forceinline__ float ex2_f(float x) { return __builtin_amdgcn_exp2f(x); }
__device__ __forceinline__ float sigm(float x) { return rcp_f(1.0f + ex2_f(-LOG2E * x)); }

// exact bf16x8 negation: flip sign bits (== (__bf16)(-x) under RNE)
__device__ __forceinline__ bf16x8 negbf8(bf16x8 v) {
  uint4 u = __builtin_bit_cast(uint4, v);
  u.x ^= 0x80008000u; u.y ^= 0x80008000u; u.z ^= 0x80008000u; u.w ^= 0x80008000u;
  return __builtin_bit_cast(bf16x8, u);
}

// 16-lane (row) sum, bit-identical to shfl_xor 1,2,4,8 tree, all VALU via DPP.
__device__ __forceinline__ float dpp_sum16(float v) {
  int x;
  x = __builtin_amdgcn_update_dpp(0, __builtin_bit_cast(int, v), 0xB1, 0xF, 0xF, false);  // quad_perm xor1
  v += __builtin_bit_cast(float, x);
  x = __builtin_amdgcn_update_dpp(0, __builtin_bit_cast(int, v), 0x4E, 0xF, 0xF, false);  // quad_perm xor2
  v += __builtin_bit_cast(float, x);
  x = __builtin_amdgcn_update_dpp(0, __builtin_bit_cast(int, v), 0x141, 0xF, 0xF, false); // row_half_mirror
  v += __builtin_bit_cast(float, x);
  x = __builtin_amdgcn_update_dpp(0, __builtin_bit_cast(int, v), 0x140, 0xF, 0xF, false); // row_mirror
  v += __builtin_bit_cast(float, x);
  return v;
}

__global__ void ems_fin(const unsigned int* __restrict__ c, float* __restrict__ out) {
  if (threadIdx.x == 0) out[0] = (float)(*c) * (1.0f / 32768.0f);
}

// Mt[e2][e] = sum_{E'} Q[e][E'] K[e2][E']; also zeroes the active-slot counter.
__global__ void __launch_bounds__(128)
ems_mt(const float* __restrict__ wqr, const float* __restrict__ wqi,
       const float* __restrict__ wkr, const float* __restrict__ wki,
       unsigned short* __restrict__ mt, unsigned int* __restrict__ cnt)
{
  if (blockIdx.x == 0 && threadIdx.x == 0) *cnt = 0u;
  __shared__ float sK[128];
  const int e2 = (int)blockIdx.x;
  const int e  = (int)threadIdx.x;
  float kv;
  if (e < 64) kv = (e2 < 64) ? wkr[e*64 + e2]      : -wki[e*64 + (e2-64)];
  else        kv = (e2 < 64) ? wki[(e-64)*64 + e2] :  wkr[(e-64)*64 + (e2-64)];
  sK[e] = kv;
  __syncthreads();
  float acc = 0.0f;
  #pragma unroll 8
  for (int Ep = 0; Ep < 64; ++Ep) {
    float q = (e < 64) ? wqr[Ep*64 + e] : -wqi[Ep*64 + (e-64)];
    acc += q * sK[Ep];
  }
  #pragma unroll 8
  for (int Ep = 0; Ep < 64; ++Ep) {
    float q = (e < 64) ? wqi[Ep*64 + e] : wqr[Ep*64 + (e-64)];
    acc += q * sK[64 + Ep];
  }
  mt[e2*128 + e] = f2bf(acc);
}

__global__ void __launch_bounds__(512, 4)
ems_main(const float* __restrict__ z_real, const float* __restrict__ z_imag,
         const float* __restrict__ mem,    const float* __restrict__ ptrv,
         const float* __restrict__ ctrl,
         const float* __restrict__ wvr,    const float* __restrict__ wvi,
         const unsigned short* __restrict__ mt,
         float* __restrict__ out_zr, float* __restrict__ out_zi,
         float* __restrict__ out_mem, float* __restrict__ out_ptr,
         unsigned int* __restrict__ ws_cnt)
{
  // [0..16384)     Mt bf16 [e2=128][e=128], 16B-chunk swizzle: chunk ^ (e2&15)
  // [16384..24576) Wv_r, Wv_i bf16 [e][d], 16B-chunk ^ (e&7)
  // [24576..40960) per-wave 4KB: xhat staging [16][128] (chunk^row), then
  //                dual half-SY: SYA [0..2KB) SYB [2KB..4KB), [16][64] (chunk^(s&7))
  __shared__ __align__(16) unsigned short lds[40960];

  const int tid = (int)threadIdx.x;

  for (int idx = tid; idx < 16384; idx += 512) {
    int e2 = idx >> 7, e = idx & 127;
    lds[(e2 << 7) + (((e >> 3) ^ (e2 & 15)) << 3) + (e & 7)] = mt[idx];
  }
  #pragma unroll
  for (int m = 0; m < 2; ++m) {
    const float* wp = m ? wvi : wvr;
    for (int idx = tid; idx < 4096; idx += 512) {
      int e = idx >> 6, d = idx & 63;
      lds[16384 + (m << 12) + (e << 6) + (((d >> 3) ^ (e & 7)) << 3) + (d & 7)] = f2bf(wp[idx]);
    }
  }
  __syncthreads();

  const int lane = tid & 63;
  const int wv   = tid >> 6;
  const int c    = lane & 15;   // MFMA A/B index; also slot s for S^T rows
  const int g    = lane >> 4;   // k-chunk group / C-row group
  const int d4   = lane & 31;   // coalesced staging: float4-column index

  // ---- phase stagger: 16 phases per CU; step 5632 cy (iteration period doubled) ----
  {
    int phase = (wv << 1) | (((int)blockIdx.x >> 8) & 1);
    #pragma unroll 1
    for (int i = 0; i < phase; ++i) __builtin_amdgcn_s_sleep(88);
  }

  unsigned short* SY  = &lds[24576 + (wv << 11)];   // 4KB buffer
  unsigned short* SYB = SY + 1024;                  // second 2KB half

  const f4* mem4 = (const f4*)mem;
  const f4* zr4  = (const f4*)z_real;
  const f4* zi4  = (const f4*)z_imag;
  f4* omem4 = (f4*)out_mem;

  unsigned int active_acc = 0u;
  const int b0 = (int)blockIdx.x * 8 + wv;

  // coalesced stage of one batch through the 4KB buffer; returns fragments + np
  auto stageBatch = [&](int b, bf16x8* af, bf16x8* afn, float& np_out) {
    f4 cm[8];
    #pragma unroll
    for (int k = 0; k < 8; ++k) cm[k] = mem4[b*512 + (k << 6) + lane];
    f4 z4 = (d4 < 16) ? zr4[b*16 + d4] : zi4[b*16 + (d4 - 16)];

    float pu = sigm(ctrl[b*3+0]);
    float po = sigm(ctrl[b*3+1]);
    float st = sigm(ctrl[b*3+2]);
    float rt = rcp_f(pu + po + st + 1e-6f);
    pu *= rt; po *= rt; st *= rt;
    float pm = ptrv[b*16 + ((c+15)&15)];
    float pp = ptrv[b*16 + ((c+ 1)&15)];
    float pc = ptrv[b*16 + c];
    float np = pu*pm + po*pp + st*pc;
    if (g == 0) out_ptr[b*16 + c] = np;
    unsigned long long ball = __ballot(np > 0.1f);
    active_acc += (unsigned int)__popcll(ball & 0xFFFFull);
    np_out = np;

    float om = 1.0f - pu;
    #pragma unroll
    for (int k = 0; k < 8; ++k) {
      f4 r = cm[k] * om + pu * z4;
      omem4[b*512 + (k << 6) + lane] = r;
      uint2 pk;
      pk.x = (unsigned)f2bf(r[0]) | ((unsigned)f2bf(r[1]) << 16);
      pk.y = (unsigned)f2bf(r[2]) | ((unsigned)f2bf(r[3]) << 16);
      int row = (k << 1) + (lane >> 5);
      *(uint2*)&SY[(row << 7) + (((d4 >> 1) ^ row) << 3) + ((d4 & 1) << 2)] = pk;
    }
    #pragma unroll
    for (int t = 0; t < 4; ++t)
      af[t] = *(const bf16x8*)&SY[(c << 7) + ((((t << 2) + g) ^ c) << 3)];
    afn[0] = negbf8(af[2]);
    afn[1] = negbf8(af[3]);
  };

  #pragma unroll 1
  for (int it = 0; it < PAIRS; ++it) {
    const int bA = b0 + (2*it)     * NWAVES;
    const int bB = b0 + (2*it + 1) * NWAVES;

    // ---------- sequential staging (buffer reused; same-wave DS in-order) ----------
    bf16x8 afA[4], afnA[2], afB[4], afnB[2];
    float npA, npB;
    stageBatch(bA, afA, afnA, npA);
    stageBatch(bB, afB, afnB, npB);

    // ---------- dual y = xhat*M in 2 halves; shared Mt fragments ----------
    f32x4 scA = {0.f,0.f,0.f,0.f}, scB = {0.f,0.f,0.f,0.f};
    #pragma unroll
    for (int h = 0; h < 2; ++h) {
      #pragma unroll
      for (int n2 = 0; n2 < 4; ++n2) {
        int e2 = (h << 6) + (n2 << 4) + c;
        f32x4 aA = {0.f,0.f,0.f,0.f}, aB = {0.f,0.f,0.f,0.f};
        #pragma unroll
        for (int T = 0; T < 4; ++T) {
          bf16x8 am = *(const bf16x8*)&lds[(e2 << 7) + ((((T << 2) + g) ^ c) << 3)];
          aA = __builtin_amdgcn_mfma_f32_16x16x32_bf16(am, afA[T], aA, 0, 0, 0);
          aB = __builtin_amdgcn_mfma_f32_16x16x32_bf16(am, afB[T], aB, 0, 0, 0);
        }
        int off = (c << 6) + ((((n2 << 1) + (g >> 1)) ^ (c & 7)) << 3) + ((g & 1) << 2);
        uint2 pkA, pkB;
        pkA.x = (unsigned)f2bf(aA[0]) | ((unsigned)f2bf(aA[1]) << 16);
        pkA.y = (unsigned)f2bf(aA[2]) | ((unsigned)f2bf(aA[3]) << 16);
        pkB.x = (unsigned)f2bf(aB[0]) | ((unsigned)f2bf(aB[1]) << 16);
        pkB.y = (unsigned)f2bf(aB[2]) | ((unsigned)f2bf(aB[3]) << 16);
        *(uint2*)&SY[off]  = pkA;
        *(uint2*)&SYB[off] = pkB;
      }
      #pragma unroll
      for (int Tp = 0; Tp < 2; ++Tp) {
        int off = (c << 6) + ((((Tp << 2) + g) ^ (c & 7)) << 3);
        bf16x8 yA = *(const bf16x8*)&SY[off];
        bf16x8 yB = *(const bf16x8*)&SYB[off];
        scA = __builtin_amdgcn_mfma_f32_16x16x32_bf16(afA[(h << 1) + Tp], yA, scA, 0, 0, 0);
        scB = __builtin_amdgcn_mfma_f32_16x16x32_bf16(afB[(h << 1) + Tp], yB, scB, 0, 0, 0);
      }
    }

    // ---------- dual fast softmax + fold np ----------
    float w4A[4], w4B[4];
    {
      float e0 = ex2_f(scA[0]*EXSC), e1 = ex2_f(scA[1]*EXSC);
      float e2v = ex2_f(scA[2]*EXSC), e3 = ex2_f(scA[3]*EXSC);
      float f0 = ex2_f(scB[0]*EXSC), f1 = ex2_f(scB[1]*EXSC);
      float f2v = ex2_f(scB[2]*EXSC), f3 = ex2_f(scB[3]*EXSC);
      float rA = (e0 + e1) + (e2v + e3);
      float rB = (f0 + f1) + (f2v + f3);
      rA += __shfl_xor(rA, 16, 64);  rB += __shfl_xor(rB, 16, 64);
      rA += __shfl_xor(rA, 32, 64);  rB += __shfl_xor(rB, 32, 64);
      float uA = npA * rcp_f(rA);
      float uB = npB * rcp_f(rB);
      w4A[0] = dpp_sum16(uA * e0);  w4B[0] = dpp_sum16(uB * f0);
      w4A[1] = dpp_sum16(uA * e1);  w4B[1] = dpp_sum16(uB * f1);
      w4A[2] = dpp_sum16(uA * e2v); w4B[2] = dpp_sum16(uB * f2v);
      w4A[3] = dpp_sum16(uA * e3);  w4B[3] = dpp_sum16(uB * f3);
    }

    // ---------- dual vhat (shared Wv fragments) + weighted readout ----------
    #pragma unroll
    for (int n = 0; n < 4; ++n) {
      int eb = 16384 + (((n << 4) + c) << 6);
      int e7 = c & 7;
      f32x4 arA = {0.f,0.f,0.f,0.f}, aiA = {0.f,0.f,0.f,0.f};
      f32x4 arB = {0.f,0.f,0.f,0.f}, aiB = {0.f,0.f,0.f,0.f};
      #pragma unroll
      for (int t = 0; t < 2; ++t) {
        int ch = (((t << 2) + g) ^ e7) << 3;
        bf16x8 fr = *(const bf16x8*)&lds[eb + ch];
        bf16x8 fi = *(const bf16x8*)&lds[eb + 4096 + ch];
        arA = __builtin_amdgcn_mfma_f32_16x16x32_bf16(afA[t],   fr, arA, 0,0,0);
        arB = __builtin_amdgcn_mfma_f32_16x16x32_bf16(afB[t],   fr, arB, 0,0,0);
        aiA = __builtin_amdgcn_mfma_f32_16x16x32_bf16(afA[t],   fi, aiA, 0,0,0);
        aiB = __builtin_amdgcn_mfma_f32_16x16x32_bf16(afB[t],   fi, aiB, 0,0,0);
        arA = __builtin_amdgcn_mfma_f32_16x16x32_bf16(afnA[t],  fi, arA, 0,0,0);
        arB = __builtin_amdgcn_mfma_f32_16x16x32_bf16(afnB[t],  fi, arB, 0,0,0);
        aiA = __builtin_amdgcn_mfma_f32_16x16x32_bf16(afA[t+2], fr, aiA, 0,0,0);
        aiB = __builtin_amdgcn_mfma_f32_16x16x32_bf16(afB[t+2], fr, aiB, 0,0,0);
      }
      float prrA = arA[0]*w4A[0] + arA[1]*w4A[1] + arA[2]*w4A[2] + arA[3]*w4A[3];
      float priA = aiA[0]*w4A[0] + aiA[1]*w4A[1] + aiA[2]*w4A[2] + aiA[3]*w4A[3];
      float prrB = arB[0]*w4B[0] + arB[1]*w4B[1] + arB[2]*w4B[2] + arB[3]*w4B[3];
      float priB = aiB[0]*w4B[0] + aiB[1]*w4B[1] + aiB[2]*w4B[2] + aiB[3]*w4B[3];
      prrA += __shfl_xor(prrA, 16, 64);  prrB += __shfl_xor(prrB, 16, 64);
      prrA += __shfl_xor(prrA, 32, 64);  prrB += __shfl_xor(prrB, 32, 64);
      priA += __shfl_xor(priA, 16, 64);  priB += __shfl_xor(priB, 16, 64);
      priA += __shfl_xor(priA, 32, 64);  priB += __shfl_xor(priB, 32, 64);
      if (g == 0) {
        out_zr[bA*64 + (n << 4) + c] = prrA;
        out_zr[bB*64 + (n << 4) + c] = prrB;
      }
      if (g == 1) {
        out_zi[bA*64 + (n << 4) + c] = priA;
        out_zi[bB*64 + (n << 4) + c] = priB;
      }
    }
  }

  // ---------- per-WG reduction of active-slot count, 1 atomic per WG ----------
  __syncthreads();                        // all SY use done
  unsigned int* cnt_lds = (unsigned int*)&lds[24576];
  if (tid == 0) *cnt_lds = 0u;
  __syncthreads();
  if (lane == 0) atomicAdd(cnt_lds, active_acc);
  __syncthreads();
  if (tid == 0) atomicAdd(ws_cnt, *cnt_lds);
}

extern "C" void kernel_launch(void* const* d_in, const int* in_sizes, int n_in,
                              void* d_out, int out_size, void* d_ws, size_t ws_size,
                              hipStream_t stream) {
  const float* z_real = (const float*)d_in[0];
  const float* z_imag = (const float*)d_in[1];
  const float* memp   = (const float*)d_in[2];
  const float* ptrv   = (const float*)d_in[3];
  const float* ctrl   = (const float*)d_in[4];
  const float* wq_r   = (const float*)d_in[5];
  const float* wq_i   = (const float*)d_in[6];
  const float* wk_r   = (const float*)d_in[7];
  const float* wk_i   = (const float*)d_in[8];
  const float* wv_r   = (const float*)d_in[9];
  const float* wv_i   = (const float*)d_in[10];

  float* out     = (float*)d_out;
  float* out_zr  = out;
  float* out_zi  = out + 2097152;
  float* out_mem = out + 4194304;
  float* out_ptr = out + 71303168;
  float* out_sc  = out + 71827456;

  unsigned int*   cnt = (unsigned int*)d_ws;
  unsigned short* mtp = (unsigned short*)((char*)d_ws + 1024);  // ws_size >= 33792

  ems_mt<<<128, 128, 0, stream>>>(wq_r, wq_i, wk_r, wk_i, mtp, cnt);
  ems_main<<<GRID_WG, 512, 0, stream>>>(z_real, z_imag, memp, ptrv, ctrl,
                                        wv_r, wv_i, mtp,
                                        out_zr, out_zi, out_mem, out_ptr, cnt);
  ems_fin<<<1, 64, 0, stream>>>(cnt, out_sc);
}